// Round 4
// baseline (238.401 us; speedup 1.0000x reference)
//
#include <hip/hip_runtime.h>

typedef _Float16 half8  __attribute__((ext_vector_type(8)));
typedef _Float16 half4  __attribute__((ext_vector_type(4)));
typedef float    float4v __attribute__((ext_vector_type(4)));

#define N_ROWS  65536   // 64*32*32
#define N_CODES 1024
#define DIM     256

// ---- prep (r3-verified): one wave per code. ||e||^2 + f16 hi/lo split in
// MFMA B-frag order: frag block b = nt*8+ks holds 1024 halves [hi 512][lo 512],
// chunk p = quad*16+l15 -> code = nt*16+l15, k = ks*32 + quad*8 + j.
__global__ __launch_bounds__(64)
void vq_prep(const float* __restrict__ emb, float* __restrict__ e_norm,
             _Float16* __restrict__ e_frag) {
    const int c = blockIdx.x, lane = threadIdx.x;
    const int l15 = c & 15, nt = c >> 4;
    float4v v = ((const float4v*)(emb + (size_t)c * DIM))[lane];
    half4 h, l;
    float ss = 0.f;
    #pragma unroll
    for (int j = 0; j < 4; ++j) {
        float x = v[j];
        ss += x * x;
        _Float16 hh = (_Float16)x;
        h[j] = hh;
        l[j] = (_Float16)(x - (float)hh);
    }
    const int ks = lane >> 3, q = (lane >> 1) & 3, jb = (lane & 1) * 4;
    _Float16* p = e_frag + ((size_t)(nt * 8 + ks)) * 1024 + (q * 16 + l15) * 8 + jb;
    *(half4*)p = h;
    *(half4*)(p + 512) = l;
    #pragma unroll
    for (int m = 32; m >= 1; m >>= 1) ss += __shfl_xor(ss, m, 64);
    if (lane == 0) e_norm[c] = ss;
}

// ---- main: 512 thr (8 waves), block = 512 rows x 256 codes.
// B pass-slice (128 codes, full K, hi/lo = 128 KB) staged in LDS once per pass
// (2 barriers/pass total). A streamed from global fp32 with inline hi/lo split.
// Wave = 64 rows x 128 codes/pass, acc[4][8][4] = 128 VGPRs.
__global__ __launch_bounds__(512, 2)
void vq_main(const float* __restrict__ z,
             const _Float16* __restrict__ e_frag,
             const float* __restrict__ e_norm,
             float2* __restrict__ partial) {
    __shared__ alignas(16) _Float16 sB[65536];   // 128 KB

    const int t = threadIdx.x;
    const int w = t >> 6, lane = t & 63, quad = lane >> 4, l15 = lane & 15;
    const int bx = blockIdx.x;
    // XCD swizzle: the 4 code-group mates of a row-block share bx&7 (same XCD)
    const int cg = (bx >> 3) & 3;
    const int rb = (bx & 7) | ((bx >> 5) << 3);
    const int rowbase = rb * 512 + w * 64;

    float bs[4][4];
    int   bi[4][4];
    #pragma unroll
    for (int mt = 0; mt < 4; ++mt)
        #pragma unroll
        for (int r = 0; r < 4; ++r) { bs[mt][r] = 3.4e38f; bi[mt][r] = 0; }

    for (int p = 0; p < 2; ++p) {
        if (p) __syncthreads();                  // pass-1 LDS reads done
        // stage B pass slice: 128 KB contiguous in e_frag (frag-blocked)
        {
            const _Float16* gsrc = e_frag + (size_t)(16 * cg + 8 * p) * 8192;
            #pragma unroll
            for (int rr = 0; rr < 16; ++rr) {
                const int off = rr * 4096 + t * 8;
                *(half8*)(sB + off) = *(const half8*)(gsrc + off);
            }
        }
        __syncthreads();

        float nrm[8];
        #pragma unroll
        for (int ntl = 0; ntl < 8; ++ntl)
            nrm[ntl] = e_norm[cg * 256 + p * 128 + ntl * 16 + l15];

        float4v acc[4][8] = {};

        for (int ks = 0; ks < 8; ++ks) {
            // A: 4 row-frags from global, inline f16 hi/lo split (VALU pipe)
            half8 ah[4], al[4];
            #pragma unroll
            for (int mt = 0; mt < 4; ++mt) {
                const float* ap = z + (size_t)(rowbase + mt * 16 + l15) * DIM
                                    + ks * 32 + quad * 8;
                float4v a0 = *(const float4v*)ap;
                float4v a1 = *(const float4v*)(ap + 4);
                #pragma unroll
                for (int j = 0; j < 4; ++j) {
                    { float x = a0[j]; _Float16 hh = (_Float16)x;
                      ah[mt][j] = hh; al[mt][j] = (_Float16)(x - (float)hh); }
                    { float x = a1[j]; _Float16 hh = (_Float16)x;
                      ah[mt][4 + j] = hh; al[mt][4 + j] = (_Float16)(x - (float)hh); }
                }
            }
            #pragma unroll
            for (int ntl = 0; ntl < 8; ++ntl) {
                const _Float16* bp = sB + (ntl * 8 + ks) * 1024 + lane * 8;
                half8 bh = *(const half8*)bp;
                half8 bl = *(const half8*)(bp + 512);
                #pragma unroll
                for (int mt = 0; mt < 4; ++mt) {
                    acc[mt][ntl] = __builtin_amdgcn_mfma_f32_16x16x32_f16(ah[mt], bh, acc[mt][ntl], 0, 0, 0);
                    acc[mt][ntl] = __builtin_amdgcn_mfma_f32_16x16x32_f16(ah[mt], bl, acc[mt][ntl], 0, 0, 0);
                    acc[mt][ntl] = __builtin_amdgcn_mfma_f32_16x16x32_f16(al[mt], bh, acc[mt][ntl], 0, 0, 0);
                }
            }
        }

        // merge this pass into per-lane best (codes ascend over p,ntl: strict <
        // keeps lowest index; C/D layout col=l15, row=quad*4+r)
        #pragma unroll
        for (int mt = 0; mt < 4; ++mt)
            #pragma unroll
            for (int ntl = 0; ntl < 8; ++ntl) {
                const int code = cg * 256 + p * 128 + ntl * 16 + l15;
                #pragma unroll
                for (int r = 0; r < 4; ++r) {
                    float s = nrm[ntl] - 2.0f * acc[mt][ntl][r];
                    if (s < bs[mt][r]) { bs[mt][r] = s; bi[mt][r] = code; }
                }
            }
    }

    // one 16-lane reduce at the end (same-row lanes = l15 group)
    #pragma unroll
    for (int m = 1; m < 16; m <<= 1)
        #pragma unroll
        for (int mt = 0; mt < 4; ++mt)
            #pragma unroll
            for (int r = 0; r < 4; ++r) {
                float s2 = __shfl_xor(bs[mt][r], m, 64);
                int   i2 = __shfl_xor(bi[mt][r], m, 64);
                if (s2 < bs[mt][r] || (s2 == bs[mt][r] && i2 < bi[mt][r])) {
                    bs[mt][r] = s2; bi[mt][r] = i2;
                }
            }

    if (l15 == 0) {
        #pragma unroll
        for (int mt = 0; mt < 4; ++mt)
            #pragma unroll
            for (int r = 0; r < 4; ++r) {
                const int row = rowbase + mt * 16 + quad * 4 + r;
                float2 pr; pr.x = bs[mt][r]; pr.y = (float)bi[mt][r];
                partial[(size_t)row * 4 + cg] = pr;
            }
    }
}

// ---- final argmin over 4 code-group partials per row ----
__global__ __launch_bounds__(256)
void vq_reduce(const float2* __restrict__ partial, float* __restrict__ idxf) {
    const int r = blockIdx.x * 256 + threadIdx.x;
    const float2* p = partial + (size_t)r * 4;
    float bsv = p[0].x, biv = p[0].y;
    #pragma unroll
    for (int s = 1; s < 4; ++s) {
        float2 v = p[s];
        if (v.x < bsv || (v.x == bsv && v.y < biv)) { bsv = v.x; biv = v.y; }
    }
    idxf[r] = biv;
}

// ---- one wave per row: lane i copies float4 #i of the winning code row ----
__global__ __launch_bounds__(256)
void vq_gather(const float* __restrict__ emb,
               const float* __restrict__ idxf,
               float* __restrict__ zq) {
    const int tid  = blockIdx.x * 256 + threadIdx.x;
    const int r    = tid >> 6;
    const int lane = tid & 63;
    const int idx  = (int)idxf[r];
    const float4* ep = (const float4*)(emb + (size_t)idx * DIM);
    ((float4*)(zq + (size_t)r * DIM))[lane] = ep[lane];
}

extern "C" void kernel_launch(void* const* d_in, const int* in_sizes, int n_in,
                              void* d_out, int out_size, void* d_ws, size_t ws_size,
                              hipStream_t stream) {
    const float* z   = (const float*)d_in[0];   // (64,32,32,256) fp32
    const float* emb = (const float*)d_in[1];   // (1024,256) fp32

    float* zq   = (float*)d_out;                        // output 0: 16,777,216 f
    float* idxf = zq + (size_t)N_ROWS * DIM;            // output 1: 65,536 f

    // scratch: e_norm (4 KB pad) + e_frag (1 MB) + partial (2 MB)
    const size_t need = 4096 + (size_t)N_CODES * DIM * 2 * sizeof(_Float16)
                      + (size_t)N_ROWS * 4 * sizeof(float2);
    char* base = (ws_size >= need) ? (char*)d_ws : (char*)d_out;  // zq area safe:
                                                                  // gather writes it last
    float*    e_norm  = (float*)base;
    _Float16* e_frag  = (_Float16*)(base + 4096);
    float2*   partial = (float2*)(e_frag + (size_t)N_CODES * DIM * 2);

    vq_prep<<<N_CODES, 64, 0, stream>>>(emb, e_norm, e_frag);
    vq_main<<<512, 512, 0, stream>>>(z, e_frag, e_norm, partial);
    vq_reduce<<<N_ROWS / 256, 256, 0, stream>>>(partial, idxf);
    vq_gather<<<(N_ROWS * 64) / 256, 256, 0, stream>>>(emb, idxf, zq);
}